// Round 8
// baseline (1424.947 us; speedup 1.0000x reference)
//
#include <hip/hip_runtime.h>

#define N_D 128
#define N_H 256
#define EPSV 1e-5f
#define STAT_ROWS 256
#define NS1 16     // xstats slices
#define NS2 32     // gemm1-stats slices
#define NB 1024    // row-range buckets
#define PERB 2304  // staged capacity per bucket (mean 1563, +18 sigma)
#define CPAD 16    // cursor padding: one counter per 64B line

typedef unsigned short u16;
typedef __attribute__((ext_vector_type(8))) short short8;
typedef __attribute__((ext_vector_type(4))) float floatx4;

__device__ __forceinline__ float bf2f(unsigned u) {
    return __uint_as_float(u << 16);
}
__device__ __forceinline__ u16 f2bf(float f) {
    unsigned u = __float_as_uint(f);
    return (u16)((u + 0x7FFFu + ((u >> 16) & 1u)) >> 16);
}

// ------- convert input fp32 -> xbf cols 0..127 (bf16) -------
__global__ __launch_bounds__(256) void convin_kernel(
    const float* __restrict__ input, u16* __restrict__ xbf, int n)
{
    int gid = blockIdx.x * 256 + threadIdx.x;
    if (gid < n * 32) {
        int r = gid >> 5, c4 = (gid & 31) * 4;
        float4 v = *(const float4*)&input[(size_t)r * N_D + c4];
        unsigned p0 = f2bf(v.x) | ((unsigned)f2bf(v.y) << 16);
        unsigned p1 = f2bf(v.z) | ((unsigned)f2bf(v.w) << 16);
        *(uint2*)&xbf[(size_t)r * 256 + c4] = make_uint2(p0, p1);
    }
}

// ------- bucket edges by row-range; ONE global atomic per (block,bucket).
// R2/R4/R5 all issued 1.6M atomicAdd-returns and all landed 75-92us --
// the device-scope atomic-return primitive is the wall, not target layout.
// Here: LDS histogram -> 262K reservation atomics (6x fewer) -> LDS-cursor
// placement into contiguous per-block runs (line-merging writes). -------
__global__ __launch_bounds__(1024) void bucket_kernel(
    const int* __restrict__ rows, const int* __restrict__ cols,
    const float* __restrict__ vals, int* __restrict__ cursor,
    int2* __restrict__ staged, int E, unsigned inv_pr, int per_rows)
{
    __shared__ int hist[NB];
    __shared__ int base[NB];
    __shared__ int lcnt[NB];
    int t = threadIdx.x;
    hist[t] = 0;
    __syncthreads();
    int per = (E + (int)gridDim.x - 1) / (int)gridDim.x;
    int lo = blockIdx.x * per;
    int hi = min(E, lo + per);
    for (int e = lo + t; e < hi; e += 1024) {
        int b = (int)__umulhi((unsigned)rows[e], inv_pr);
        atomicAdd(&hist[b], 1);
    }
    __syncthreads();
    {
        int h = hist[t];
        base[t] = h ? atomicAdd(&cursor[t * CPAD], h) : 0;
        lcnt[t] = 0;
    }
    __syncthreads();
    for (int e = lo + t; e < hi; e += 1024) {
        int r = rows[e];
        int b = (int)__umulhi((unsigned)r, inv_pr);
        int rl = r - b * per_rows;                       // < 98, 7 bits
        int idx = base[b] + atomicAdd(&lcnt[b], 1);      // LDS cursor
        if (idx < PERB)                                  // P(overflow) ~ 1e-30
            staged[(size_t)b * PERB + idx] =
                make_int2(cols[e] | (rl << 17), __float_as_int(vals[e]));
    }
}

// ------- fused place+aggregate: one block per bucket; LDS f32 accumulators
// acc[98][128]; wave-gathers x[col] (4-deep ILP) and ds_add_f32 accumulates;
// writes bf16 agg half. Replaces scatter_place + CSR edges + old aggregate
// + all scans + convin's count atomics. -------
__global__ __launch_bounds__(256) void bucket_aggregate_kernel(
    const unsigned* __restrict__ xin, const int* __restrict__ cursor,
    const int2* __restrict__ staged, unsigned* __restrict__ xout,
    int n, int per_rows)
{
    __shared__ float acc[100 * 128];   // 51.2KB -> 3 blocks/CU
    int b = blockIdx.x;
    int t = threadIdx.x;
    int r0 = b * per_rows;
    if (r0 >= n) return;
    int lane = t & 63, w = t >> 6;
    for (int i = t; i < per_rows * 128; i += 256) acc[i] = 0.f;
    __syncthreads();
    int count = min(cursor[b * CPAD], PERB);
    const int2* sb = staged + (size_t)b * PERB;

#define ACCUM(ee, pp) { \
        int rl_ = ((unsigned)(ee).x) >> 17; \
        float v_ = __int_as_float((ee).y); \
        atomicAdd(&acc[rl_ * 128 + 2 * lane],     v_ * bf2f((pp) & 0xFFFF)); \
        atomicAdd(&acc[rl_ * 128 + 2 * lane + 1], v_ * bf2f((pp) >> 16)); }

    int i = w;
    for (; i + 12 < count; i += 16) {
        int2 e0 = sb[i];
        int2 e1 = sb[i + 4];
        int2 e2 = sb[i + 8];
        int2 e3 = sb[i + 12];
        unsigned p0 = xin[(size_t)(e0.x & 0x1FFFF) * 128 + lane];
        unsigned p1 = xin[(size_t)(e1.x & 0x1FFFF) * 128 + lane];
        unsigned p2 = xin[(size_t)(e2.x & 0x1FFFF) * 128 + lane];
        unsigned p3 = xin[(size_t)(e3.x & 0x1FFFF) * 128 + lane];
        ACCUM(e0, p0); ACCUM(e1, p1); ACCUM(e2, p2); ACCUM(e3, p3);
    }
    for (; i < count; i += 4) {
        int2 e0 = sb[i];
        unsigned p0 = xin[(size_t)(e0.x & 0x1FFFF) * 128 + lane];
        ACCUM(e0, p0);
    }
#undef ACCUM
    __syncthreads();
    for (int rr = w; rr < per_rows; rr += 4) {
        int r = r0 + rr;
        if (r < n)
            xout[(size_t)r * 128 + 64 + lane] =
                f2bf(acc[rr * 128 + 2 * lane]) |
                ((unsigned)f2bf(acc[rr * 128 + 2 * lane + 1]) << 16);
    }
}

// ------------- column sums/sumsq of xbf, SLICED accumulators -------------
__global__ __launch_bounds__(256) void xstats_kernel(
    const u16* __restrict__ xbf, float* __restrict__ s1s, int n)
{
    int t = threadIdx.x;
    int r0 = blockIdx.x * STAT_ROWS;
    int r1 = min(n, r0 + STAT_ROWS);
    float s = 0.f, q = 0.f;
    for (int r = r0; r < r1; ++r) {
        float x = bf2f((unsigned)xbf[(size_t)r * 256 + t]);
        s += x; q += x * x;
    }
    float* base = s1s + (size_t)(blockIdx.x & (NS1 - 1)) * 512;
    atomicAdd(&base[t], s);
    atomicAdd(&base[256 + t], q);
}

// ------------- BN1 affine coefficients (reduces NS1 slices) -------------
__global__ __launch_bounds__(256) void prep1a_kernel(
    const float* __restrict__ s1s,
    const float* __restrict__ gamma1, const float* __restrict__ beta1,
    float* __restrict__ a1, float* __restrict__ c1, float n)
{
    int t = threadIdx.x;
    float sum = 0.f, sq = 0.f;
#pragma unroll
    for (int s = 0; s < NS1; ++s) {
        sum += s1s[s * 512 + t];
        sq  += s1s[s * 512 + 256 + t];
    }
    float mu = sum / n;
    float var = sq / n - mu * mu;
    float rs = rsqrtf(var + EPSV);
    float a = rs * gamma1[t];
    a1[t] = a;
    c1[t] = beta1[t] - mu * a;
}

// ------- W1bt[nIdx][k] = bf16(a1[k]*W1[k][nIdx]) ; b1p = c1@W1 + b1 -------
__global__ __launch_bounds__(256) void convw1_kernel(
    const float* __restrict__ W1, const float* __restrict__ a1,
    const float* __restrict__ c1, const float* __restrict__ b1,
    u16* __restrict__ W1bt, float* __restrict__ b1p)
{
    __shared__ float red[256];
    int nIdx = blockIdx.x;
    int k = threadIdx.x;
    float w = W1[(size_t)k * N_H + nIdx];
    W1bt[(size_t)nIdx * 256 + k] = f2bf(a1[k] * w);
    red[k] = c1[k] * w;
    __syncthreads();
    for (int s = 128; s > 0; s >>= 1) {
        if (k < s) red[k] += red[k + s];
        __syncthreads();
    }
    if (k == 0) b1p[nIdx] = red[0] + b1[nIdx];
}

// ------------- W2bt[nIdx][k] = bf16(W2[k][nIdx]) -------------
__global__ __launch_bounds__(256) void convw2_kernel(
    const float* __restrict__ W2, u16* __restrict__ W2bt)
{
    int nIdx = blockIdx.x;
    int k = threadIdx.x;
    W2bt[(size_t)nIdx * 256 + k] = f2bf(W2[(size_t)k * N_D + nIdx]);
}

// ------------- BN2 per-column affine (reduces NS2 slices) -------------
__global__ __launch_bounds__(256) void prep2_kernel(
    const float* __restrict__ s2s,
    const float* __restrict__ gamma2, const float* __restrict__ beta2,
    float* __restrict__ a2, float* __restrict__ c2, float n)
{
    int t = threadIdx.x;
    float sum = 0.f, sq = 0.f;
#pragma unroll
    for (int s = 0; s < NS2; ++s) {
        sum += s2s[s * 512 + t];
        sq  += s2s[s * 512 + 256 + t];
    }
    float mu = sum / n;
    float var = sq / n - mu * mu;
    float rs = rsqrtf(var + EPSV);
    float a = rs * gamma2[t];
    a2[t] = a;
    c2[t] = beta2[t] - mu * a;
}

// ------------- GEMM1: register-direct, sliced stats atomics -------------
__global__ __launch_bounds__(256, 3) void gemm1_kernel(
    const u16* __restrict__ xbf, const u16* __restrict__ W1bt,
    const float* __restrict__ b1p, u16* __restrict__ ybf,
    float* __restrict__ s2s, int n)
{
    __shared__ __align__(16) u16 T[128 * 136];   // +8 pad per row
    __shared__ float ssum[128];
    __shared__ float ssq[128];
    int t = threadIdx.x;
    int w = t >> 6, l = t & 63;
    int row0 = blockIdx.x * 128;
    int col0 = blockIdx.y * 128;
    int wrow = (w & 1) * 64, wcol = (w >> 1) * 64;
    int lm = l & 15, lq = l >> 4;
    if (t < 128) { ssum[t] = 0.f; ssq[t] = 0.f; }

    floatx4 acc[4][4];
#pragma unroll
    for (int i = 0; i < 4; ++i)
#pragma unroll
        for (int j = 0; j < 4; ++j) acc[i][j] = (floatx4){0.f, 0.f, 0.f, 0.f};

    const u16* Ab = xbf + (size_t)(row0 + wrow + lm) * 256 + lq * 8;
    const u16* Bb = W1bt + (size_t)(col0 + wcol + lm) * 256 + lq * 8;

    short8 a0[4], b0[4], a1[4], b1[4];
#pragma unroll
    for (int f = 0; f < 4; ++f) {
        a0[f] = *(const short8*)&Ab[f * 4096];
        b0[f] = *(const short8*)&Bb[f * 4096];
    }
#pragma unroll
    for (int kk = 0; kk < 4; ++kk) {
        int k1 = kk * 64 + 32;
#pragma unroll
        for (int f = 0; f < 4; ++f) {
            a1[f] = *(const short8*)&Ab[f * 4096 + k1];
            b1[f] = *(const short8*)&Bb[f * 4096 + k1];
        }
#pragma unroll
        for (int fm = 0; fm < 4; ++fm)
#pragma unroll
            for (int fn = 0; fn < 4; ++fn)
                acc[fm][fn] = __builtin_amdgcn_mfma_f32_16x16x32_bf16(
                    a0[fm], b0[fn], acc[fm][fn], 0, 0, 0);
        if (kk < 3) {
            int k2 = kk * 64 + 64;
#pragma unroll
            for (int f = 0; f < 4; ++f) {
                a0[f] = *(const short8*)&Ab[f * 4096 + k2];
                b0[f] = *(const short8*)&Bb[f * 4096 + k2];
            }
        }
#pragma unroll
        for (int fm = 0; fm < 4; ++fm)
#pragma unroll
            for (int fn = 0; fn < 4; ++fn)
                acc[fm][fn] = __builtin_amdgcn_mfma_f32_16x16x32_bf16(
                    a1[fm], b1[fn], acc[fm][fn], 0, 0, 0);
    }

    __syncthreads();   // orders ssum/ssq init before atomics below
    float cs[4] = {0.f, 0.f, 0.f, 0.f};
    float cq[4] = {0.f, 0.f, 0.f, 0.f};
#pragma unroll
    for (int fn = 0; fn < 4; ++fn) {
        int cl = wcol + fn * 16 + lm;
        float bb = b1p[col0 + cl];
#pragma unroll
        for (int fm = 0; fm < 4; ++fm) {
            int rl = wrow + fm * 16 + lq * 4;
#pragma unroll
            for (int i = 0; i < 4; ++i) {
                float v = acc[fm][fn][i] + bb;
                T[(rl + i) * 136 + cl] = f2bf(v);
                if (row0 + rl + i < n) { cs[fn] += v; cq[fn] += v * v; }
            }
        }
        atomicAdd(&ssum[cl], cs[fn]);
        atomicAdd(&ssq[cl], cq[fn]);
    }
    __syncthreads();
    float* sbase = s2s + (size_t)(blockIdx.x & (NS2 - 1)) * 512;
    if (t < 128) {
        atomicAdd(&sbase[col0 + t], ssum[t]);
        atomicAdd(&sbase[256 + col0 + t], ssq[t]);
    }
    // coalesced writeback: 16 lanes x uint4 = one full 256B row-half per pass
#pragma unroll
    for (int p = 0; p < 8; ++p) {
        int r = p * 16 + (t >> 4);
        if (row0 + r < n)
            *(uint4*)&ybf[(size_t)(row0 + r) * 256 + col0 + (t & 15) * 8] =
                *(const uint4*)&T[r * 136 + (t & 15) * 8];
    }
}

__device__ __forceinline__ short8 bn_relu_pack(
    uint4 raw, float4 aa0, float4 aa1, float4 cc0, float4 cc1)
{
    float z0 = fmaxf(bf2f(raw.x & 0xFFFF) * aa0.x + cc0.x, 0.f);
    float z1 = fmaxf(bf2f(raw.x >> 16)    * aa0.y + cc0.y, 0.f);
    float z2 = fmaxf(bf2f(raw.y & 0xFFFF) * aa0.z + cc0.z, 0.f);
    float z3 = fmaxf(bf2f(raw.y >> 16)    * aa0.w + cc0.w, 0.f);
    float z4 = fmaxf(bf2f(raw.z & 0xFFFF) * aa1.x + cc1.x, 0.f);
    float z5 = fmaxf(bf2f(raw.z >> 16)    * aa1.y + cc1.y, 0.f);
    float z6 = fmaxf(bf2f(raw.w & 0xFFFF) * aa1.z + cc1.z, 0.f);
    float z7 = fmaxf(bf2f(raw.w >> 16)    * aa1.w + cc1.w, 0.f);
    uint4 pk;
    pk.x = f2bf(z0) | ((unsigned)f2bf(z1) << 16);
    pk.y = f2bf(z2) | ((unsigned)f2bf(z3) << 16);
    pk.z = f2bf(z4) | ((unsigned)f2bf(z5) << 16);
    pk.w = f2bf(z6) | ((unsigned)f2bf(z7) << 16);
    return *(short8*)&pk;
}

// ------------- GEMM2: register-direct, BN2+relu fused in-register per frag. -------------
__global__ __launch_bounds__(256, 3) void gemm2_kernel(
    const u16* __restrict__ ybf, const u16* __restrict__ W2bt,
    const float* __restrict__ a2, const float* __restrict__ c2,
    const float* __restrict__ b2, float* __restrict__ out, int n)
{
    int t = threadIdx.x;
    int w = t >> 6, l = t & 63;
    int row0 = blockIdx.x * 128;
    int wrow = (w & 1) * 64, wcol = (w >> 1) * 64;
    int lm = l & 15, lq = l >> 4;

    floatx4 acc[4][4];
#pragma unroll
    for (int i = 0; i < 4; ++i)
#pragma unroll
        for (int j = 0; j < 4; ++j) acc[i][j] = (floatx4){0.f, 0.f, 0.f, 0.f};

    const u16* Ab = ybf + (size_t)(row0 + wrow + lm) * 256 + lq * 8;
    const u16* Bb = W2bt + (size_t)(wcol + lm) * 256 + lq * 8;
    int kbase = lq * 8;

    uint4 r0[4], r1[4];
#pragma unroll
    for (int f = 0; f < 4; ++f) r0[f] = *(const uint4*)&Ab[f * 4096];

#pragma unroll
    for (int kk = 0; kk < 4; ++kk) {
        int ka = kk * 64, k1 = ka + 32;
#pragma unroll
        for (int f = 0; f < 4; ++f) r1[f] = *(const uint4*)&Ab[f * 4096 + k1];
        {
            int kc = ka + kbase;
            float4 aa0 = *(const float4*)&a2[kc];
            float4 aa1 = *(const float4*)&a2[kc + 4];
            float4 cc0 = *(const float4*)&c2[kc];
            float4 cc1 = *(const float4*)&c2[kc + 4];
            short8 af[4], bf_[4];
#pragma unroll
            for (int f = 0; f < 4; ++f) {
                af[f] = bn_relu_pack(r0[f], aa0, aa1, cc0, cc1);
                bf_[f] = *(const short8*)&Bb[f * 4096 + ka];
            }
#pragma unroll
            for (int fm = 0; fm < 4; ++fm)
#pragma unroll
                for (int fn = 0; fn < 4; ++fn)
                    acc[fm][fn] = __builtin_amdgcn_mfma_f32_16x16x32_bf16(
                        af[fm], bf_[fn], acc[fm][fn], 0, 0, 0);
        }
        if (kk < 3) {
            int k2 = ka + 64;
#pragma unroll
            for (int f = 0; f < 4; ++f) r0[f] = *(const uint4*)&Ab[f * 4096 + k2];
        }
        {
            int kc = k1 + kbase;
            float4 aa0 = *(const float4*)&a2[kc];
            float4 aa1 = *(const float4*)&a2[kc + 4];
            float4 cc0 = *(const float4*)&c2[kc];
            float4 cc1 = *(const float4*)&c2[kc + 4];
            short8 af[4], bf_[4];
#pragma unroll
            for (int f = 0; f < 4; ++f) {
                af[f] = bn_relu_pack(r1[f], aa0, aa1, cc0, cc1);
                bf_[f] = *(const short8*)&Bb[f * 4096 + k1];
            }
#pragma unroll
            for (int fm = 0; fm < 4; ++fm)
#pragma unroll
                for (int fn = 0; fn < 4; ++fn)
                    acc[fm][fn] = __builtin_amdgcn_mfma_f32_16x16x32_bf16(
                        af[fm], bf_[fn], acc[fm][fn], 0, 0, 0);
        }
    }

#pragma unroll
    for (int fn = 0; fn < 4; ++fn) {
        int c = wcol + fn * 16 + lm;
        float bb = b2[c];
#pragma unroll
        for (int fm = 0; fm < 4; ++fm) {
            int rbase = row0 + wrow + fm * 16 + lq * 4;
#pragma unroll
            for (int i = 0; i < 4; ++i) {
                int r = rbase + i;
                if (r < n) out[(size_t)r * N_D + c] = acc[fm][fn][i] + bb;
            }
        }
    }
}

extern "C" void kernel_launch(void* const* d_in, const int* in_sizes, int n_in,
                              void* d_out, int out_size, void* d_ws, size_t ws_size,
                              hipStream_t stream)
{
    const float* input    = (const float*)d_in[0];
    const int*   adj_rows = (const int*)d_in[1];
    const int*   adj_cols = (const int*)d_in[2];
    const float* adj_vals = (const float*)d_in[3];
    const float* gamma1   = (const float*)d_in[4];
    const float* beta1    = (const float*)d_in[5];
    const float* W1       = (const float*)d_in[6];
    const float* b1       = (const float*)d_in[7];
    const float* gamma2   = (const float*)d_in[8];
    const float* beta2    = (const float*)d_in[9];
    const float* W2       = (const float*)d_in[10];
    const float* b2       = (const float*)d_in[11];

    int n = in_sizes[0] / N_D;   // 100000
    int E = in_sizes[1];         // 1600000
    size_t n_pad = ((size_t)n + 127) & ~(size_t)127;

    u16* xbf = (u16*)d_ws;                         // n_pad*256 bf16
    u16* ybf = xbf + n_pad * 256;                  // n_pad*256 bf16
    int2* staged = (int2*)ybf;                     // NB*PERB int2 (18.9MB, consumed pre-gemm1)
    u16* W1bt = ybf + n_pad * 256;                 // 256*256 bf16
    u16* W2bt = W1bt + 256 * 256;                  // 128*256 bf16
    float* stats  = (float*)(W2bt + 128 * 256);
    float* a1     = stats;
    float* c1     = stats + 256;
    float* b1p    = stats + 512;
    float* a2     = stats + 768;
    float* c2     = stats + 1024;
    float* s1s    = stats + 1280;                  // NS1*512 floats
    float* s2s    = s1s + NS1 * 512;               // NS2*512 floats
    int* cursor   = (int*)(s2s + NS2 * 512);       // NB*CPAD ints (64B-padded)

    hipMemsetAsync(cursor, 0, (size_t)NB * CPAD * sizeof(int), stream);
    hipMemsetAsync(s1s, 0, (size_t)(NS1 + NS2) * 512 * sizeof(float), stream);

    convin_kernel<<<(n * 32 + 255) / 256, 256, 0, stream>>>(input, xbf, n);
    convw2_kernel<<<128, 256, 0, stream>>>(W2, W2bt);

    // bucket magic: b = umulhi(r, inv_pr) == r / per_rows for r < 2^17
    int per_rows = (n + NB - 1) / NB;                       // 98
    unsigned inv_pr = (unsigned)((((unsigned long long)1 << 32) + per_rows - 1) / per_rows);

    bucket_kernel<<<256, 1024, 0, stream>>>(
        adj_rows, adj_cols, adj_vals, cursor, staged, E, inv_pr, per_rows);
    bucket_aggregate_kernel<<<NB, 256, 0, stream>>>(
        (const unsigned*)xbf, cursor, staged, (unsigned*)xbf, n, per_rows);

    xstats_kernel<<<(n + STAT_ROWS - 1) / STAT_ROWS, 256, 0, stream>>>(xbf, s1s, n);

    prep1a_kernel<<<1, 256, 0, stream>>>(s1s, gamma1, beta1, a1, c1, (float)n);
    convw1_kernel<<<256, 256, 0, stream>>>(W1, a1, c1, b1, W1bt, b1p);

    dim3 g1((unsigned)(n_pad / 128), 2);
    gemm1_kernel<<<g1, 256, 0, stream>>>(xbf, W1bt, b1p, ybf, s2s, n);

    prep2_kernel<<<1, 256, 0, stream>>>(s2s, gamma2, beta2, a2, c2, (float)n);

    gemm2_kernel<<<(unsigned)(n_pad / 128), 256, 0, stream>>>(ybf, W2bt, a2, c2, b2, (float*)d_out, n);
}

// Round 9
// 460.860 us; speedup vs baseline: 3.0919x; 3.0919x over previous
//
#include <hip/hip_runtime.h>

#define N_D 128
#define N_H 256
#define EPSV 1e-5f
#define STAT_ROWS 256
#define NS1 16     // xstats slices
#define NS2 32     // gemm1-stats slices
#define NB 1024    // row-range buckets
#define PERB 2304  // staged capacity per bucket (mean 1563, +18 sigma)
#define CPAD 16    // cursor padding: one counter per 64B line

typedef unsigned short u16;
typedef __attribute__((ext_vector_type(8))) short short8;
typedef __attribute__((ext_vector_type(4))) float floatx4;

__device__ __forceinline__ float bf2f(unsigned u) {
    return __uint_as_float(u << 16);
}
__device__ __forceinline__ u16 f2bf(float f) {
    unsigned u = __float_as_uint(f);
    return (u16)((u + 0x7FFFu + ((u >> 16) & 1u)) >> 16);
}

// ------- convert input fp32 -> xbf cols 0..127 (bf16); no atomics -------
__global__ __launch_bounds__(256) void convin_kernel(
    const float* __restrict__ input, u16* __restrict__ xbf, int n)
{
    int gid = blockIdx.x * 256 + threadIdx.x;
    if (gid < n * 32) {
        int r = gid >> 5, c4 = (gid & 31) * 4;
        float4 v = *(const float4*)&input[(size_t)r * N_D + c4];
        unsigned p0 = f2bf(v.x) | ((unsigned)f2bf(v.y) << 16);
        unsigned p1 = f2bf(v.z) | ((unsigned)f2bf(v.w) << 16);
        *(uint2*)&xbf[(size_t)r * 256 + c4] = make_uint2(p0, p1);
    }
}

// ------- bucket edges by row-range; ONE global atomic per (block,bucket).
// (R6 reservation scheme: 262K atomic-returns instead of 1.6M.) -------
__global__ __launch_bounds__(1024) void bucket_kernel(
    const int* __restrict__ rows, const int* __restrict__ cols,
    const float* __restrict__ vals, int* __restrict__ cursor,
    int2* __restrict__ staged, int E, unsigned inv_pr, int per_rows)
{
    __shared__ int hist[NB];
    __shared__ int base[NB];
    __shared__ int lcnt[NB];
    int t = threadIdx.x;
    hist[t] = 0;
    __syncthreads();
    int per = (E + (int)gridDim.x - 1) / (int)gridDim.x;
    int lo = blockIdx.x * per;
    int hi = min(E, lo + per);
    for (int e = lo + t; e < hi; e += 1024) {
        int b = (int)__umulhi((unsigned)rows[e], inv_pr);
        atomicAdd(&hist[b], 1);
    }
    __syncthreads();
    {
        int h = hist[t];
        base[t] = h ? atomicAdd(&cursor[t * CPAD], h) : 0;
        lcnt[t] = 0;
    }
    __syncthreads();
    for (int e = lo + t; e < hi; e += 1024) {
        int r = rows[e];
        int b = (int)__umulhi((unsigned)r, inv_pr);
        int rl = r - b * per_rows;                       // < 98, 7 bits
        int idx = base[b] + atomicAdd(&lcnt[b], 1);      // LDS cursor
        if (idx < PERB)                                  // P(overflow) ~ 1e-30
            staged[(size_t)b * PERB + idx] =
                make_int2(cols[e] | (rl << 17), __float_as_int(vals[e]));
    }
}

// ------- exclusive scan of 1024 bucket counts -> bucketBase -------
__global__ __launch_bounds__(1024) void scan_buckets_kernel(
    const int* __restrict__ cursor, int* __restrict__ bucketBase)
{
    __shared__ int sm[NB];
    int t = threadIdx.x;
    int v = min(cursor[t * CPAD], PERB);
    sm[t] = v;
    __syncthreads();
    for (int off = 1; off < NB; off <<= 1) {
        int x = (t >= off) ? sm[t - off] : 0;
        __syncthreads();
        sm[t] += x;
        __syncthreads();
    }
    bucketBase[t] = sm[t] - v;
}

// ------- place: block per bucket. LDS histogram of 98 local rows -> LDS scan
// -> CSR edges + rowPtr + cnt. Bucket = row range, so CSR offsets are
// bucketBase[b] + local scan: no n-wide count/scan kernels, no global atomics.
// (R8 lesson: do NOT fuse aggregation here -- placement is cheap, streaming;
// aggregation needs the 100K-wave TLP of the dedicated kernel.) -------
__global__ __launch_bounds__(256) void place_kernel(
    const int* __restrict__ cursor, const int* __restrict__ bucketBase,
    const int2* __restrict__ staged, int2* __restrict__ edges,
    int* __restrict__ rowPtr, int* __restrict__ cnt, int n, int per_rows)
{
    __shared__ int hist[128];
    __shared__ int scn[128];
    __shared__ int lcnt[128];
    int b = blockIdx.x;
    int t = threadIdx.x;
    int r0 = b * per_rows;
    if (r0 >= n) return;
    if (t < 128) { hist[t] = 0; lcnt[t] = 0; }
    __syncthreads();
    int count = min(cursor[b * CPAD], PERB);
    const int2* sb = staged + (size_t)b * PERB;
    for (int i = t; i < count; i += 256)
        atomicAdd(&hist[((unsigned)sb[i].x) >> 17], 1);
    __syncthreads();
    if (t < 128) scn[t] = hist[t];
    __syncthreads();
    for (int off = 1; off < 128; off <<= 1) {
        int x = (t < 128 && t >= off) ? scn[t - off] : 0;
        __syncthreads();
        if (t < 128) scn[t] += x;
        __syncthreads();
    }
    int base = bucketBase[b];
    if (t < per_rows && r0 + t < n) {
        rowPtr[r0 + t] = base + scn[t] - hist[t];   // exclusive
        cnt[r0 + t] = hist[t];
    }
    __syncthreads();
    for (int i = t; i < count; i += 256) {
        int2 en = sb[i];
        int rl = ((unsigned)en.x) >> 17;
        int idx = atomicAdd(&lcnt[rl], 1);
        edges[base + scn[rl] - hist[rl] + idx] = make_int2(en.x & 0x1FFFF, en.y);
    }
}

// ------- gather-reduce, one wave per row (100K waves -> latency hidden
// by TLP), 4-deep ILP -------
__global__ __launch_bounds__(256) void aggregate_kernel(
    const unsigned* __restrict__ xin,
    const int* __restrict__ rowPtr, const int* __restrict__ cnt,
    const int2* __restrict__ edges,
    unsigned* __restrict__ xout, int n)
{
    int wave = (blockIdx.x * 256 + threadIdx.x) >> 6;
    if (wave >= n) return;
    int lane = threadIdx.x & 63;
    int e = rowPtr[wave];
    int end = e + cnt[wave];
    float2 a0 = make_float2(0.f, 0.f);
    float2 a1 = make_float2(0.f, 0.f);
    float2 a2 = make_float2(0.f, 0.f);
    float2 a3 = make_float2(0.f, 0.f);
    if ((e & 1) && e < end) {
        int2 ed = edges[e];
        unsigned p = xin[(size_t)ed.x * 128 + lane];
        float v = __int_as_float(ed.y);
        a0.x += v * bf2f(p & 0xFFFF);
        a0.y += v * bf2f(p >> 16);
        ++e;
    }
    for (; e + 3 < end; e += 4) {
        int4 q0 = *(const int4*)&edges[e];
        int4 q1 = *(const int4*)&edges[e + 2];
        unsigned p0 = xin[(size_t)q0.x * 128 + lane];
        unsigned p1 = xin[(size_t)q0.z * 128 + lane];
        unsigned p2 = xin[(size_t)q1.x * 128 + lane];
        unsigned p3 = xin[(size_t)q1.z * 128 + lane];
        float v0 = __int_as_float(q0.y);
        float v1 = __int_as_float(q0.w);
        float v2 = __int_as_float(q1.y);
        float v3 = __int_as_float(q1.w);
        a0.x += v0 * bf2f(p0 & 0xFFFF); a0.y += v0 * bf2f(p0 >> 16);
        a1.x += v1 * bf2f(p1 & 0xFFFF); a1.y += v1 * bf2f(p1 >> 16);
        a2.x += v2 * bf2f(p2 & 0xFFFF); a2.y += v2 * bf2f(p2 >> 16);
        a3.x += v3 * bf2f(p3 & 0xFFFF); a3.y += v3 * bf2f(p3 >> 16);
    }
    for (; e < end; ++e) {
        int2 ed = edges[e];
        unsigned p = xin[(size_t)ed.x * 128 + lane];
        float v = __int_as_float(ed.y);
        a0.x += v * bf2f(p & 0xFFFF);
        a0.y += v * bf2f(p >> 16);
    }
    a0.x += a1.x + a2.x;
    a0.y += a1.y + a2.y;
    a0.x += a3.x;
    a0.y += a3.y;
    xout[(size_t)wave * 128 + 64 + lane] = f2bf(a0.x) | ((unsigned)f2bf(a0.y) << 16);
}

// ------------- column sums/sumsq of xbf, SLICED accumulators -------------
__global__ __launch_bounds__(256) void xstats_kernel(
    const u16* __restrict__ xbf, float* __restrict__ s1s, int n)
{
    int t = threadIdx.x;
    int r0 = blockIdx.x * STAT_ROWS;
    int r1 = min(n, r0 + STAT_ROWS);
    float s = 0.f, q = 0.f;
    for (int r = r0; r < r1; ++r) {
        float x = bf2f((unsigned)xbf[(size_t)r * 256 + t]);
        s += x; q += x * x;
    }
    float* base = s1s + (size_t)(blockIdx.x & (NS1 - 1)) * 512;
    atomicAdd(&base[t], s);
    atomicAdd(&base[256 + t], q);
}

// ------------- BN1 affine coefficients (reduces NS1 slices) -------------
__global__ __launch_bounds__(256) void prep1a_kernel(
    const float* __restrict__ s1s,
    const float* __restrict__ gamma1, const float* __restrict__ beta1,
    float* __restrict__ a1, float* __restrict__ c1, float n)
{
    int t = threadIdx.x;
    float sum = 0.f, sq = 0.f;
#pragma unroll
    for (int s = 0; s < NS1; ++s) {
        sum += s1s[s * 512 + t];
        sq  += s1s[s * 512 + 256 + t];
    }
    float mu = sum / n;
    float var = sq / n - mu * mu;
    float rs = rsqrtf(var + EPSV);
    float a = rs * gamma1[t];
    a1[t] = a;
    c1[t] = beta1[t] - mu * a;
}

// ------- W1bt[nIdx][k] = bf16(a1[k]*W1[k][nIdx]) ; b1p = c1@W1 + b1 -------
__global__ __launch_bounds__(256) void convw1_kernel(
    const float* __restrict__ W1, const float* __restrict__ a1,
    const float* __restrict__ c1, const float* __restrict__ b1,
    u16* __restrict__ W1bt, float* __restrict__ b1p)
{
    __shared__ float red[256];
    int nIdx = blockIdx.x;
    int k = threadIdx.x;
    float w = W1[(size_t)k * N_H + nIdx];
    W1bt[(size_t)nIdx * 256 + k] = f2bf(a1[k] * w);
    red[k] = c1[k] * w;
    __syncthreads();
    for (int s = 128; s > 0; s >>= 1) {
        if (k < s) red[k] += red[k + s];
        __syncthreads();
    }
    if (k == 0) b1p[nIdx] = red[0] + b1[nIdx];
}

// ------------- W2bt[nIdx][k] = bf16(W2[k][nIdx]) -------------
__global__ __launch_bounds__(256) void convw2_kernel(
    const float* __restrict__ W2, u16* __restrict__ W2bt)
{
    int nIdx = blockIdx.x;
    int k = threadIdx.x;
    W2bt[(size_t)nIdx * 256 + k] = f2bf(W2[(size_t)k * N_D + nIdx]);
}

// ------------- BN2 per-column affine (reduces NS2 slices) -------------
__global__ __launch_bounds__(256) void prep2_kernel(
    const float* __restrict__ s2s,
    const float* __restrict__ gamma2, const float* __restrict__ beta2,
    float* __restrict__ a2, float* __restrict__ c2, float n)
{
    int t = threadIdx.x;
    float sum = 0.f, sq = 0.f;
#pragma unroll
    for (int s = 0; s < NS2; ++s) {
        sum += s2s[s * 512 + t];
        sq  += s2s[s * 512 + 256 + t];
    }
    float mu = sum / n;
    float var = sq / n - mu * mu;
    float rs = rsqrtf(var + EPSV);
    float a = rs * gamma2[t];
    a2[t] = a;
    c2[t] = beta2[t] - mu * a;
}

// ------------- GEMM1: register-direct, sliced stats atomics -------------
__global__ __launch_bounds__(256, 3) void gemm1_kernel(
    const u16* __restrict__ xbf, const u16* __restrict__ W1bt,
    const float* __restrict__ b1p, u16* __restrict__ ybf,
    float* __restrict__ s2s, int n)
{
    __shared__ __align__(16) u16 T[128 * 136];   // +8 pad per row
    __shared__ float ssum[128];
    __shared__ float ssq[128];
    int t = threadIdx.x;
    int w = t >> 6, l = t & 63;
    int row0 = blockIdx.x * 128;
    int col0 = blockIdx.y * 128;
    int wrow = (w & 1) * 64, wcol = (w >> 1) * 64;
    int lm = l & 15, lq = l >> 4;
    if (t < 128) { ssum[t] = 0.f; ssq[t] = 0.f; }

    floatx4 acc[4][4];
#pragma unroll
    for (int i = 0; i < 4; ++i)
#pragma unroll
        for (int j = 0; j < 4; ++j) acc[i][j] = (floatx4){0.f, 0.f, 0.f, 0.f};

    const u16* Ab = xbf + (size_t)(row0 + wrow + lm) * 256 + lq * 8;
    const u16* Bb = W1bt + (size_t)(col0 + wcol + lm) * 256 + lq * 8;

    short8 a0[4], b0[4], a1[4], b1[4];
#pragma unroll
    for (int f = 0; f < 4; ++f) {
        a0[f] = *(const short8*)&Ab[f * 4096];
        b0[f] = *(const short8*)&Bb[f * 4096];
    }
#pragma unroll
    for (int kk = 0; kk < 4; ++kk) {
        int k1 = kk * 64 + 32;
#pragma unroll
        for (int f = 0; f < 4; ++f) {
            a1[f] = *(const short8*)&Ab[f * 4096 + k1];
            b1[f] = *(const short8*)&Bb[f * 4096 + k1];
        }
#pragma unroll
        for (int fm = 0; fm < 4; ++fm)
#pragma unroll
            for (int fn = 0; fn < 4; ++fn)
                acc[fm][fn] = __builtin_amdgcn_mfma_f32_16x16x32_bf16(
                    a0[fm], b0[fn], acc[fm][fn], 0, 0, 0);
        if (kk < 3) {
            int k2 = kk * 64 + 64;
#pragma unroll
            for (int f = 0; f < 4; ++f) {
                a0[f] = *(const short8*)&Ab[f * 4096 + k2];
                b0[f] = *(const short8*)&Bb[f * 4096 + k2];
            }
        }
#pragma unroll
        for (int fm = 0; fm < 4; ++fm)
#pragma unroll
            for (int fn = 0; fn < 4; ++fn)
                acc[fm][fn] = __builtin_amdgcn_mfma_f32_16x16x32_bf16(
                    a1[fm], b1[fn], acc[fm][fn], 0, 0, 0);
    }

    __syncthreads();   // orders ssum/ssq init before atomics below
    float cs[4] = {0.f, 0.f, 0.f, 0.f};
    float cq[4] = {0.f, 0.f, 0.f, 0.f};
#pragma unroll
    for (int fn = 0; fn < 4; ++fn) {
        int cl = wcol + fn * 16 + lm;
        float bb = b1p[col0 + cl];
#pragma unroll
        for (int fm = 0; fm < 4; ++fm) {
            int rl = wrow + fm * 16 + lq * 4;
#pragma unroll
            for (int i = 0; i < 4; ++i) {
                float v = acc[fm][fn][i] + bb;
                T[(rl + i) * 136 + cl] = f2bf(v);
                if (row0 + rl + i < n) { cs[fn] += v; cq[fn] += v * v; }
            }
        }
        atomicAdd(&ssum[cl], cs[fn]);
        atomicAdd(&ssq[cl], cq[fn]);
    }
    __syncthreads();
    float* sbase = s2s + (size_t)(blockIdx.x & (NS2 - 1)) * 512;
    if (t < 128) {
        atomicAdd(&sbase[col0 + t], ssum[t]);
        atomicAdd(&sbase[256 + col0 + t], ssq[t]);
    }
    // coalesced writeback: 16 lanes x uint4 = one full 256B row-half per pass
#pragma unroll
    for (int p = 0; p < 8; ++p) {
        int r = p * 16 + (t >> 4);
        if (row0 + r < n)
            *(uint4*)&ybf[(size_t)(row0 + r) * 256 + col0 + (t & 15) * 8] =
                *(const uint4*)&T[r * 136 + (t & 15) * 8];
    }
}

__device__ __forceinline__ short8 bn_relu_pack(
    uint4 raw, float4 aa0, float4 aa1, float4 cc0, float4 cc1)
{
    float z0 = fmaxf(bf2f(raw.x & 0xFFFF) * aa0.x + cc0.x, 0.f);
    float z1 = fmaxf(bf2f(raw.x >> 16)    * aa0.y + cc0.y, 0.f);
    float z2 = fmaxf(bf2f(raw.y & 0xFFFF) * aa0.z + cc0.z, 0.f);
    float z3 = fmaxf(bf2f(raw.y >> 16)    * aa0.w + cc0.w, 0.f);
    float z4 = fmaxf(bf2f(raw.z & 0xFFFF) * aa1.x + cc1.x, 0.f);
    float z5 = fmaxf(bf2f(raw.z >> 16)    * aa1.y + cc1.y, 0.f);
    float z6 = fmaxf(bf2f(raw.w & 0xFFFF) * aa1.z + cc1.z, 0.f);
    float z7 = fmaxf(bf2f(raw.w >> 16)    * aa1.w + cc1.w, 0.f);
    uint4 pk;
    pk.x = f2bf(z0) | ((unsigned)f2bf(z1) << 16);
    pk.y = f2bf(z2) | ((unsigned)f2bf(z3) << 16);
    pk.z = f2bf(z4) | ((unsigned)f2bf(z5) << 16);
    pk.w = f2bf(z6) | ((unsigned)f2bf(z7) << 16);
    return *(short8*)&pk;
}

// ------------- GEMM2: register-direct, BN2+relu fused in-register per frag. -------------
__global__ __launch_bounds__(256, 3) void gemm2_kernel(
    const u16* __restrict__ ybf, const u16* __restrict__ W2bt,
    const float* __restrict__ a2, const float* __restrict__ c2,
    const float* __restrict__ b2, float* __restrict__ out, int n)
{
    int t = threadIdx.x;
    int w = t >> 6, l = t & 63;
    int row0 = blockIdx.x * 128;
    int wrow = (w & 1) * 64, wcol = (w >> 1) * 64;
    int lm = l & 15, lq = l >> 4;

    floatx4 acc[4][4];
#pragma unroll
    for (int i = 0; i < 4; ++i)
#pragma unroll
        for (int j = 0; j < 4; ++j) acc[i][j] = (floatx4){0.f, 0.f, 0.f, 0.f};

    const u16* Ab = ybf + (size_t)(row0 + wrow + lm) * 256 + lq * 8;
    const u16* Bb = W2bt + (size_t)(wcol + lm) * 256 + lq * 8;
    int kbase = lq * 8;

    uint4 r0[4], r1[4];
#pragma unroll
    for (int f = 0; f < 4; ++f) r0[f] = *(const uint4*)&Ab[f * 4096];

#pragma unroll
    for (int kk = 0; kk < 4; ++kk) {
        int ka = kk * 64, k1 = ka + 32;
#pragma unroll
        for (int f = 0; f < 4; ++f) r1[f] = *(const uint4*)&Ab[f * 4096 + k1];
        {
            int kc = ka + kbase;
            float4 aa0 = *(const float4*)&a2[kc];
            float4 aa1 = *(const float4*)&a2[kc + 4];
            float4 cc0 = *(const float4*)&c2[kc];
            float4 cc1 = *(const float4*)&c2[kc + 4];
            short8 af[4], bf_[4];
#pragma unroll
            for (int f = 0; f < 4; ++f) {
                af[f] = bn_relu_pack(r0[f], aa0, aa1, cc0, cc1);
                bf_[f] = *(const short8*)&Bb[f * 4096 + ka];
            }
#pragma unroll
            for (int fm = 0; fm < 4; ++fm)
#pragma unroll
                for (int fn = 0; fn < 4; ++fn)
                    acc[fm][fn] = __builtin_amdgcn_mfma_f32_16x16x32_bf16(
                        af[fm], bf_[fn], acc[fm][fn], 0, 0, 0);
        }
        if (kk < 3) {
            int k2 = ka + 64;
#pragma unroll
            for (int f = 0; f < 4; ++f) r0[f] = *(const uint4*)&Ab[f * 4096 + k2];
        }
        {
            int kc = k1 + kbase;
            float4 aa0 = *(const float4*)&a2[kc];
            float4 aa1 = *(const float4*)&a2[kc + 4];
            float4 cc0 = *(const float4*)&c2[kc];
            float4 cc1 = *(const float4*)&c2[kc + 4];
            short8 af[4], bf_[4];
#pragma unroll
            for (int f = 0; f < 4; ++f) {
                af[f] = bn_relu_pack(r1[f], aa0, aa1, cc0, cc1);
                bf_[f] = *(const short8*)&Bb[f * 4096 + k1];
            }
#pragma unroll
            for (int fm = 0; fm < 4; ++fm)
#pragma unroll
                for (int fn = 0; fn < 4; ++fn)
                    acc[fm][fn] = __builtin_amdgcn_mfma_f32_16x16x32_bf16(
                        af[fm], bf_[fn], acc[fm][fn], 0, 0, 0);
        }
    }

#pragma unroll
    for (int fn = 0; fn < 4; ++fn) {
        int c = wcol + fn * 16 + lm;
        float bb = b2[c];
#pragma unroll
        for (int fm = 0; fm < 4; ++fm) {
            int rbase = row0 + wrow + fm * 16 + lq * 4;
#pragma unroll
            for (int i = 0; i < 4; ++i) {
                int r = rbase + i;
                if (r < n) out[(size_t)r * N_D + c] = acc[fm][fn][i] + bb;
            }
        }
    }
}

extern "C" void kernel_launch(void* const* d_in, const int* in_sizes, int n_in,
                              void* d_out, int out_size, void* d_ws, size_t ws_size,
                              hipStream_t stream)
{
    const float* input    = (const float*)d_in[0];
    const int*   adj_rows = (const int*)d_in[1];
    const int*   adj_cols = (const int*)d_in[2];
    const float* adj_vals = (const float*)d_in[3];
    const float* gamma1   = (const float*)d_in[4];
    const float* beta1    = (const float*)d_in[5];
    const float* W1       = (const float*)d_in[6];
    const float* b1       = (const float*)d_in[7];
    const float* gamma2   = (const float*)d_in[8];
    const float* beta2    = (const float*)d_in[9];
    const float* W2       = (const float*)d_in[10];
    const float* b2       = (const float*)d_in[11];

    int n = in_sizes[0] / N_D;   // 100000
    int E = in_sizes[1];         // 1600000
    size_t n_pad = ((size_t)n + 127) & ~(size_t)127;

    u16* xbf = (u16*)d_ws;                         // n_pad*256 bf16
    u16* ybf = xbf + n_pad * 256;                  // n_pad*256 bf16
    int2* edges = (int2*)ybf;                      // E int2 (aliases ybf; consumed pre-gemm1)
    int2* staged = edges + E;                      // NB*PERB int2 (also in ybf region)
    u16* W1bt = ybf + n_pad * 256;                 // 256*256 bf16
    u16* W2bt = W1bt + 256 * 256;                  // 128*256 bf16
    float* stats  = (float*)(W2bt + 128 * 256);
    float* a1     = stats;
    float* c1     = stats + 256;
    float* b1p    = stats + 512;
    float* a2     = stats + 768;
    float* c2     = stats + 1024;
    float* s1s    = stats + 1280;                  // NS1*512 floats
    float* s2s    = s1s + NS1 * 512;               // NS2*512 floats
    int* cursor     = (int*)(s2s + NS2 * 512);     // NB*CPAD ints (64B-padded)
    int* bucketBase = cursor + NB * CPAD;          // NB ints
    int* rowPtr     = bucketBase + NB;             // n ints
    int* cnt        = rowPtr + n;                  // n ints

    hipMemsetAsync(cursor, 0, (size_t)NB * CPAD * sizeof(int), stream);
    hipMemsetAsync(s1s, 0, (size_t)(NS1 + NS2) * 512 * sizeof(float), stream);

    convin_kernel<<<(n * 32 + 255) / 256, 256, 0, stream>>>(input, xbf, n);
    convw2_kernel<<<128, 256, 0, stream>>>(W2, W2bt);

    // bucket magic: b = umulhi(r, inv_pr) == r / per_rows for r < 2^17
    int per_rows = (n + NB - 1) / NB;                       // 98
    unsigned inv_pr = (unsigned)((((unsigned long long)1 << 32) + per_rows - 1) / per_rows);

    bucket_kernel<<<256, 1024, 0, stream>>>(
        adj_rows, adj_cols, adj_vals, cursor, staged, E, inv_pr, per_rows);
    scan_buckets_kernel<<<1, 1024, 0, stream>>>(cursor, bucketBase);
    place_kernel<<<NB, 256, 0, stream>>>(
        cursor, bucketBase, staged, edges, rowPtr, cnt, n, per_rows);

    aggregate_kernel<<<(n + 3) / 4, 256, 0, stream>>>(
        (const unsigned*)xbf, rowPtr, cnt, edges, (unsigned*)xbf, n);

    xstats_kernel<<<(n + STAT_ROWS - 1) / STAT_ROWS, 256, 0, stream>>>(xbf, s1s, n);

    prep1a_kernel<<<1, 256, 0, stream>>>(s1s, gamma1, beta1, a1, c1, (float)n);
    convw1_kernel<<<256, 256, 0, stream>>>(W1, a1, c1, b1, W1bt, b1p);

    dim3 g1((unsigned)(n_pad / 128), 2);
    gemm1_kernel<<<g1, 256, 0, stream>>>(xbf, W1bt, b1p, ybf, s2s, n);

    prep2_kernel<<<1, 256, 0, stream>>>(s2s, gamma2, beta2, a2, c2, (float)n);

    gemm2_kernel<<<(unsigned)(n_pad / 128), 256, 0, stream>>>(ybf, W2bt, a2, c2, b2, (float*)d_out, n);
}

// Round 10
// 452.976 us; speedup vs baseline: 3.1457x; 1.0174x over previous
//
#include <hip/hip_runtime.h>

#define N_D 128
#define N_H 256
#define EPSV 1e-5f
#define STAT_ROWS 256
#define NS1 16     // xstats slices
#define NS2 32     // gemm1-stats slices
#define NB 1024    // row-range buckets
#define PERB 2304  // staged capacity per bucket (mean 1563, +18 sigma)
#define CPAD 16    // cursor padding: one counter per 64B line

typedef unsigned short u16;
typedef __attribute__((ext_vector_type(8))) short short8;
typedef __attribute__((ext_vector_type(4))) float floatx4;

__device__ __forceinline__ float bf2f(unsigned u) {
    return __uint_as_float(u << 16);
}
__device__ __forceinline__ u16 f2bf(float f) {
    unsigned u = __float_as_uint(f);
    return (u16)((u + 0x7FFFu + ((u >> 16) & 1u)) >> 16);
}

// ------- convert input fp32 -> xbf cols 0..127 (bf16); no atomics -------
__global__ __launch_bounds__(256) void convin_kernel(
    const float* __restrict__ input, u16* __restrict__ xbf, int n)
{
    int gid = blockIdx.x * 256 + threadIdx.x;
    if (gid < n * 32) {
        int r = gid >> 5, c4 = (gid & 31) * 4;
        float4 v = *(const float4*)&input[(size_t)r * N_D + c4];
        unsigned p0 = f2bf(v.x) | ((unsigned)f2bf(v.y) << 16);
        unsigned p1 = f2bf(v.z) | ((unsigned)f2bf(v.w) << 16);
        *(uint2*)&xbf[(size_t)r * 256 + c4] = make_uint2(p0, p1);
    }
}

// ------- bucket edges by row-range; ONE global atomic per (block,bucket). -------
__global__ __launch_bounds__(1024) void bucket_kernel(
    const int* __restrict__ rows, const int* __restrict__ cols,
    const float* __restrict__ vals, int* __restrict__ cursor,
    int2* __restrict__ staged, int E, unsigned inv_pr, int per_rows)
{
    __shared__ int hist[NB];
    __shared__ int base[NB];
    __shared__ int lcnt[NB];
    int t = threadIdx.x;
    hist[t] = 0;
    __syncthreads();
    int per = (E + (int)gridDim.x - 1) / (int)gridDim.x;
    int lo = blockIdx.x * per;
    int hi = min(E, lo + per);
    for (int e = lo + t; e < hi; e += 1024) {
        int b = (int)__umulhi((unsigned)rows[e], inv_pr);
        atomicAdd(&hist[b], 1);
    }
    __syncthreads();
    {
        int h = hist[t];
        base[t] = h ? atomicAdd(&cursor[t * CPAD], h) : 0;
        lcnt[t] = 0;
    }
    __syncthreads();
    for (int e = lo + t; e < hi; e += 1024) {
        int r = rows[e];
        int b = (int)__umulhi((unsigned)r, inv_pr);
        int rl = r - b * per_rows;                       // < 98, 7 bits
        int idx = base[b] + atomicAdd(&lcnt[b], 1);      // LDS cursor
        if (idx < PERB)                                  // P(overflow) ~ 1e-30
            staged[(size_t)b * PERB + idx] =
                make_int2(cols[e] | (rl << 17), __float_as_int(vals[e]));
    }
}

// ------- exclusive scan of 1024 bucket counts -> bucketBase -------
__global__ __launch_bounds__(1024) void scan_buckets_kernel(
    const int* __restrict__ cursor, int* __restrict__ bucketBase)
{
    __shared__ int sm[NB];
    int t = threadIdx.x;
    int v = min(cursor[t * CPAD], PERB);
    sm[t] = v;
    __syncthreads();
    for (int off = 1; off < NB; off <<= 1) {
        int x = (t >= off) ? sm[t - off] : 0;
        __syncthreads();
        sm[t] += x;
        __syncthreads();
    }
    bucketBase[t] = sm[t] - v;
}

// ------- place: block per bucket; LDS histogram+scan -> CSR edges/rowPtr/cnt -------
__global__ __launch_bounds__(256) void place_kernel(
    const int* __restrict__ cursor, const int* __restrict__ bucketBase,
    const int2* __restrict__ staged, int2* __restrict__ edges,
    int* __restrict__ rowPtr, int* __restrict__ cnt, int n, int per_rows)
{
    __shared__ int hist[128];
    __shared__ int scn[128];
    __shared__ int lcnt[128];
    int b = blockIdx.x;
    int t = threadIdx.x;
    int r0 = b * per_rows;
    if (r0 >= n) return;
    if (t < 128) { hist[t] = 0; lcnt[t] = 0; }
    __syncthreads();
    int count = min(cursor[b * CPAD], PERB);
    const int2* sb = staged + (size_t)b * PERB;
    for (int i = t; i < count; i += 256)
        atomicAdd(&hist[((unsigned)sb[i].x) >> 17], 1);
    __syncthreads();
    if (t < 128) scn[t] = hist[t];
    __syncthreads();
    for (int off = 1; off < 128; off <<= 1) {
        int x = (t < 128 && t >= off) ? scn[t - off] : 0;
        __syncthreads();
        if (t < 128) scn[t] += x;
        __syncthreads();
    }
    int base = bucketBase[b];
    if (t < per_rows && r0 + t < n) {
        rowPtr[r0 + t] = base + scn[t] - hist[t];   // exclusive
        cnt[r0 + t] = hist[t];
    }
    __syncthreads();
    for (int i = t; i < count; i += 256) {
        int2 en = sb[i];
        int rl = ((unsigned)en.x) >> 17;
        int idx = atomicAdd(&lcnt[rl], 1);
        edges[base + scn[rl] - hist[rl] + idx] = make_int2(en.x & 0x1FFFF, en.y);
    }
}

// ------- gather-reduce: 2 edges per wave (half-wave each, uint2 gathers).
// R9 counters: VALU-issue ~31us floor at 1 edge/wave/4B-lane loads, HBM 35%.
// Half-wave split halves per-edge VALU (addr calc, unpack shared across 8B
// lanes) and doubles edges in flight (8/wave). Cross-half __shfl reduce,
// lanes 0-31 write uint2 (coalesced 256B/row). -------
__global__ __launch_bounds__(256) void aggregate_kernel(
    const unsigned* __restrict__ xin,
    const int* __restrict__ rowPtr, const int* __restrict__ cnt,
    const int2* __restrict__ edges,
    unsigned* __restrict__ xout, int n)
{
    int wave = (blockIdx.x * 256 + threadIdx.x) >> 6;
    if (wave >= n) return;
    int lane = threadIdx.x & 63;
    int half = lane >> 5;
    int ll = lane & 31;
    const uint2* xin2 = (const uint2*)xin;      // row stride 64 uint2
    int e = rowPtr[wave];
    int end = e + cnt[wave];
    float4 a0 = {0.f,0.f,0.f,0.f}, a1 = {0.f,0.f,0.f,0.f};
    float4 a2 = {0.f,0.f,0.f,0.f}, a3 = {0.f,0.f,0.f,0.f};

#define ACC4(acc, pp, vv) { \
        acc.x += (vv) * bf2f((pp).x & 0xFFFF); \
        acc.y += (vv) * bf2f((pp).x >> 16); \
        acc.z += (vv) * bf2f((pp).y & 0xFFFF); \
        acc.w += (vv) * bf2f((pp).y >> 16); }

    // peel one edge if start is odd (keeps int4 loads 16B-aligned)
    if ((e & 1) && e < end) {
        int2 ed = edges[e];
        float v = half ? 0.f : __int_as_float(ed.y);
        uint2 p = xin2[(size_t)ed.x * 64 + ll];
        ACC4(a0, p, v);
        ++e;
    }
    // main: 8 edges per iter (4 aligned pairs)
    for (; e + 7 < end; e += 8) {
        int4 q0 = *(const int4*)&edges[e];
        int4 q1 = *(const int4*)&edges[e + 2];
        int4 q2 = *(const int4*)&edges[e + 4];
        int4 q3 = *(const int4*)&edges[e + 6];
        int   c0 = half ? q0.z : q0.x;
        int   c1 = half ? q1.z : q1.x;
        int   c2 = half ? q2.z : q2.x;
        int   c3 = half ? q3.z : q3.x;
        float v0 = __int_as_float(half ? q0.w : q0.y);
        float v1 = __int_as_float(half ? q1.w : q1.y);
        float v2 = __int_as_float(half ? q2.w : q2.y);
        float v3 = __int_as_float(half ? q3.w : q3.y);
        uint2 p0 = xin2[(size_t)c0 * 64 + ll];
        uint2 p1 = xin2[(size_t)c1 * 64 + ll];
        uint2 p2 = xin2[(size_t)c2 * 64 + ll];
        uint2 p3 = xin2[(size_t)c3 * 64 + ll];
        ACC4(a0, p0, v0);
        ACC4(a1, p1, v1);
        ACC4(a2, p2, v2);
        ACC4(a3, p3, v3);
    }
    // pair tail
    for (; e + 1 < end; e += 2) {
        int4 q0 = *(const int4*)&edges[e];
        int   c0 = half ? q0.z : q0.x;
        float v0 = __int_as_float(half ? q0.w : q0.y);
        uint2 p0 = xin2[(size_t)c0 * 64 + ll];
        ACC4(a0, p0, v0);
    }
    // final single edge: half 1 contributes 0
    if (e < end) {
        int2 ed = edges[e];
        float v = half ? 0.f : __int_as_float(ed.y);
        uint2 p = xin2[(size_t)ed.x * 64 + ll];
        ACC4(a0, p, v);
    }
#undef ACC4

    a0.x += a1.x + a2.x + a3.x;
    a0.y += a1.y + a2.y + a3.y;
    a0.z += a1.z + a2.z + a3.z;
    a0.w += a1.w + a2.w + a3.w;
    // cross-half reduce: lane ll (<32) pulls lane ll+32's partial
    float bx = __shfl(a0.x, ll + 32, 64);
    float by = __shfl(a0.y, ll + 32, 64);
    float bz = __shfl(a0.z, ll + 32, 64);
    float bw = __shfl(a0.w, ll + 32, 64);
    if (half == 0) {
        a0.x += bx; a0.y += by; a0.z += bz; a0.w += bw;
        uint2 pk;
        pk.x = f2bf(a0.x) | ((unsigned)f2bf(a0.y) << 16);
        pk.y = f2bf(a0.z) | ((unsigned)f2bf(a0.w) << 16);
        ((uint2*)xout)[(size_t)wave * 64 + 32 + ll] = pk;
    }
}

// ------------- column sums/sumsq of xbf, SLICED accumulators -------------
__global__ __launch_bounds__(256) void xstats_kernel(
    const u16* __restrict__ xbf, float* __restrict__ s1s, int n)
{
    int t = threadIdx.x;
    int r0 = blockIdx.x * STAT_ROWS;
    int r1 = min(n, r0 + STAT_ROWS);
    float s = 0.f, q = 0.f;
    for (int r = r0; r < r1; ++r) {
        float x = bf2f((unsigned)xbf[(size_t)r * 256 + t]);
        s += x; q += x * x;
    }
    float* base = s1s + (size_t)(blockIdx.x & (NS1 - 1)) * 512;
    atomicAdd(&base[t], s);
    atomicAdd(&base[256 + t], q);
}

// ------------- BN1 affine coefficients (reduces NS1 slices) -------------
__global__ __launch_bounds__(256) void prep1a_kernel(
    const float* __restrict__ s1s,
    const float* __restrict__ gamma1, const float* __restrict__ beta1,
    float* __restrict__ a1, float* __restrict__ c1, float n)
{
    int t = threadIdx.x;
    float sum = 0.f, sq = 0.f;
#pragma unroll
    for (int s = 0; s < NS1; ++s) {
        sum += s1s[s * 512 + t];
        sq  += s1s[s * 512 + 256 + t];
    }
    float mu = sum / n;
    float var = sq / n - mu * mu;
    float rs = rsqrtf(var + EPSV);
    float a = rs * gamma1[t];
    a1[t] = a;
    c1[t] = beta1[t] - mu * a;
}

// ------- W1bt[nIdx][k] = bf16(a1[k]*W1[k][nIdx]) ; b1p = c1@W1 + b1 -------
__global__ __launch_bounds__(256) void convw1_kernel(
    const float* __restrict__ W1, const float* __restrict__ a1,
    const float* __restrict__ c1, const float* __restrict__ b1,
    u16* __restrict__ W1bt, float* __restrict__ b1p)
{
    __shared__ float red[256];
    int nIdx = blockIdx.x;
    int k = threadIdx.x;
    float w = W1[(size_t)k * N_H + nIdx];
    W1bt[(size_t)nIdx * 256 + k] = f2bf(a1[k] * w);
    red[k] = c1[k] * w;
    __syncthreads();
    for (int s = 128; s > 0; s >>= 1) {
        if (k < s) red[k] += red[k + s];
        __syncthreads();
    }
    if (k == 0) b1p[nIdx] = red[0] + b1[nIdx];
}

// ------------- W2bt[nIdx][k] = bf16(W2[k][nIdx]) -------------
__global__ __launch_bounds__(256) void convw2_kernel(
    const float* __restrict__ W2, u16* __restrict__ W2bt)
{
    int nIdx = blockIdx.x;
    int k = threadIdx.x;
    W2bt[(size_t)nIdx * 256 + k] = f2bf(W2[(size_t)k * N_D + nIdx]);
}

// ------------- BN2 per-column affine (reduces NS2 slices) -------------
__global__ __launch_bounds__(256) void prep2_kernel(
    const float* __restrict__ s2s,
    const float* __restrict__ gamma2, const float* __restrict__ beta2,
    float* __restrict__ a2, float* __restrict__ c2, float n)
{
    int t = threadIdx.x;
    float sum = 0.f, sq = 0.f;
#pragma unroll
    for (int s = 0; s < NS2; ++s) {
        sum += s2s[s * 512 + t];
        sq  += s2s[s * 512 + 256 + t];
    }
    float mu = sum / n;
    float var = sq / n - mu * mu;
    float rs = rsqrtf(var + EPSV);
    float a = rs * gamma2[t];
    a2[t] = a;
    c2[t] = beta2[t] - mu * a;
}

// ------------- GEMM1: register-direct, sliced stats atomics -------------
__global__ __launch_bounds__(256, 3) void gemm1_kernel(
    const u16* __restrict__ xbf, const u16* __restrict__ W1bt,
    const float* __restrict__ b1p, u16* __restrict__ ybf,
    float* __restrict__ s2s, int n)
{
    __shared__ __align__(16) u16 T[128 * 136];   // +8 pad per row
    __shared__ float ssum[128];
    __shared__ float ssq[128];
    int t = threadIdx.x;
    int w = t >> 6, l = t & 63;
    int row0 = blockIdx.x * 128;
    int col0 = blockIdx.y * 128;
    int wrow = (w & 1) * 64, wcol = (w >> 1) * 64;
    int lm = l & 15, lq = l >> 4;
    if (t < 128) { ssum[t] = 0.f; ssq[t] = 0.f; }

    floatx4 acc[4][4];
#pragma unroll
    for (int i = 0; i < 4; ++i)
#pragma unroll
        for (int j = 0; j < 4; ++j) acc[i][j] = (floatx4){0.f, 0.f, 0.f, 0.f};

    const u16* Ab = xbf + (size_t)(row0 + wrow + lm) * 256 + lq * 8;
    const u16* Bb = W1bt + (size_t)(col0 + wcol + lm) * 256 + lq * 8;

    short8 a0[4], b0[4], a1[4], b1[4];
#pragma unroll
    for (int f = 0; f < 4; ++f) {
        a0[f] = *(const short8*)&Ab[f * 4096];
        b0[f] = *(const short8*)&Bb[f * 4096];
    }
#pragma unroll
    for (int kk = 0; kk < 4; ++kk) {
        int k1 = kk * 64 + 32;
#pragma unroll
        for (int f = 0; f < 4; ++f) {
            a1[f] = *(const short8*)&Ab[f * 4096 + k1];
            b1[f] = *(const short8*)&Bb[f * 4096 + k1];
        }
#pragma unroll
        for (int fm = 0; fm < 4; ++fm)
#pragma unroll
            for (int fn = 0; fn < 4; ++fn)
                acc[fm][fn] = __builtin_amdgcn_mfma_f32_16x16x32_bf16(
                    a0[fm], b0[fn], acc[fm][fn], 0, 0, 0);
        if (kk < 3) {
            int k2 = kk * 64 + 64;
#pragma unroll
            for (int f = 0; f < 4; ++f) {
                a0[f] = *(const short8*)&Ab[f * 4096 + k2];
                b0[f] = *(const short8*)&Bb[f * 4096 + k2];
            }
        }
#pragma unroll
        for (int fm = 0; fm < 4; ++fm)
#pragma unroll
            for (int fn = 0; fn < 4; ++fn)
                acc[fm][fn] = __builtin_amdgcn_mfma_f32_16x16x32_bf16(
                    a1[fm], b1[fn], acc[fm][fn], 0, 0, 0);
    }

    __syncthreads();   // orders ssum/ssq init before atomics below
    float cs[4] = {0.f, 0.f, 0.f, 0.f};
    float cq[4] = {0.f, 0.f, 0.f, 0.f};
#pragma unroll
    for (int fn = 0; fn < 4; ++fn) {
        int cl = wcol + fn * 16 + lm;
        float bb = b1p[col0 + cl];
#pragma unroll
        for (int fm = 0; fm < 4; ++fm) {
            int rl = wrow + fm * 16 + lq * 4;
#pragma unroll
            for (int i = 0; i < 4; ++i) {
                float v = acc[fm][fn][i] + bb;
                T[(rl + i) * 136 + cl] = f2bf(v);
                if (row0 + rl + i < n) { cs[fn] += v; cq[fn] += v * v; }
            }
        }
        atomicAdd(&ssum[cl], cs[fn]);
        atomicAdd(&ssq[cl], cq[fn]);
    }
    __syncthreads();
    float* sbase = s2s + (size_t)(blockIdx.x & (NS2 - 1)) * 512;
    if (t < 128) {
        atomicAdd(&sbase[col0 + t], ssum[t]);
        atomicAdd(&sbase[256 + col0 + t], ssq[t]);
    }
    // coalesced writeback: 16 lanes x uint4 = one full 256B row-half per pass
#pragma unroll
    for (int p = 0; p < 8; ++p) {
        int r = p * 16 + (t >> 4);
        if (row0 + r < n)
            *(uint4*)&ybf[(size_t)(row0 + r) * 256 + col0 + (t & 15) * 8] =
                *(const uint4*)&T[r * 136 + (t & 15) * 8];
    }
}

__device__ __forceinline__ short8 bn_relu_pack(
    uint4 raw, float4 aa0, float4 aa1, float4 cc0, float4 cc1)
{
    float z0 = fmaxf(bf2f(raw.x & 0xFFFF) * aa0.x + cc0.x, 0.f);
    float z1 = fmaxf(bf2f(raw.x >> 16)    * aa0.y + cc0.y, 0.f);
    float z2 = fmaxf(bf2f(raw.y & 0xFFFF) * aa0.z + cc0.z, 0.f);
    float z3 = fmaxf(bf2f(raw.y >> 16)    * aa0.w + cc0.w, 0.f);
    float z4 = fmaxf(bf2f(raw.z & 0xFFFF) * aa1.x + cc1.x, 0.f);
    float z5 = fmaxf(bf2f(raw.z >> 16)    * aa1.y + cc1.y, 0.f);
    float z6 = fmaxf(bf2f(raw.w & 0xFFFF) * aa1.z + cc1.z, 0.f);
    float z7 = fmaxf(bf2f(raw.w >> 16)    * aa1.w + cc1.w, 0.f);
    uint4 pk;
    pk.x = f2bf(z0) | ((unsigned)f2bf(z1) << 16);
    pk.y = f2bf(z2) | ((unsigned)f2bf(z3) << 16);
    pk.z = f2bf(z4) | ((unsigned)f2bf(z5) << 16);
    pk.w = f2bf(z6) | ((unsigned)f2bf(z7) << 16);
    return *(short8*)&pk;
}

// ------------- GEMM2: register-direct, BN2+relu fused in-register per frag. -------------
__global__ __launch_bounds__(256, 3) void gemm2_kernel(
    const u16* __restrict__ ybf, const u16* __restrict__ W2bt,
    const float* __restrict__ a2, const float* __restrict__ c2,
    const float* __restrict__ b2, float* __restrict__ out, int n)
{
    int t = threadIdx.x;
    int w = t >> 6, l = t & 63;
    int row0 = blockIdx.x * 128;
    int wrow = (w & 1) * 64, wcol = (w >> 1) * 64;
    int lm = l & 15, lq = l >> 4;

    floatx4 acc[4][4];
#pragma unroll
    for (int i = 0; i < 4; ++i)
#pragma unroll
        for (int j = 0; j < 4; ++j) acc[i][j] = (floatx4){0.f, 0.f, 0.f, 0.f};

    const u16* Ab = ybf + (size_t)(row0 + wrow + lm) * 256 + lq * 8;
    const u16* Bb = W2bt + (size_t)(wcol + lm) * 256 + lq * 8;
    int kbase = lq * 8;

    uint4 r0[4], r1[4];
#pragma unroll
    for (int f = 0; f < 4; ++f) r0[f] = *(const uint4*)&Ab[f * 4096];

#pragma unroll
    for (int kk = 0; kk < 4; ++kk) {
        int ka = kk * 64, k1 = ka + 32;
#pragma unroll
        for (int f = 0; f < 4; ++f) r1[f] = *(const uint4*)&Ab[f * 4096 + k1];
        {
            int kc = ka + kbase;
            float4 aa0 = *(const float4*)&a2[kc];
            float4 aa1 = *(const float4*)&a2[kc + 4];
            float4 cc0 = *(const float4*)&c2[kc];
            float4 cc1 = *(const float4*)&c2[kc + 4];
            short8 af[4], bf_[4];
#pragma unroll
            for (int f = 0; f < 4; ++f) {
                af[f] = bn_relu_pack(r0[f], aa0, aa1, cc0, cc1);
                bf_[f] = *(const short8*)&Bb[f * 4096 + ka];
            }
#pragma unroll
            for (int fm = 0; fm < 4; ++fm)
#pragma unroll
                for (int fn = 0; fn < 4; ++fn)
                    acc[fm][fn] = __builtin_amdgcn_mfma_f32_16x16x32_bf16(
                        af[fm], bf_[fn], acc[fm][fn], 0, 0, 0);
        }
        if (kk < 3) {
            int k2 = ka + 64;
#pragma unroll
            for (int f = 0; f < 4; ++f) r0[f] = *(const uint4*)&Ab[f * 4096 + k2];
        }
        {
            int kc = k1 + kbase;
            float4 aa0 = *(const float4*)&a2[kc];
            float4 aa1 = *(const float4*)&a2[kc + 4];
            float4 cc0 = *(const float4*)&c2[kc];
            float4 cc1 = *(const float4*)&c2[kc + 4];
            short8 af[4], bf_[4];
#pragma unroll
            for (int f = 0; f < 4; ++f) {
                af[f] = bn_relu_pack(r1[f], aa0, aa1, cc0, cc1);
                bf_[f] = *(const short8*)&Bb[f * 4096 + k1];
            }
#pragma unroll
            for (int fm = 0; fm < 4; ++fm)
#pragma unroll
                for (int fn = 0; fn < 4; ++fn)
                    acc[fm][fn] = __builtin_amdgcn_mfma_f32_16x16x32_bf16(
                        af[fm], bf_[fn], acc[fm][fn], 0, 0, 0);
        }
    }

#pragma unroll
    for (int fn = 0; fn < 4; ++fn) {
        int c = wcol + fn * 16 + lm;
        float bb = b2[c];
#pragma unroll
        for (int fm = 0; fm < 4; ++fm) {
            int rbase = row0 + wrow + fm * 16 + lq * 4;
#pragma unroll
            for (int i = 0; i < 4; ++i) {
                int r = rbase + i;
                if (r < n) out[(size_t)r * N_D + c] = acc[fm][fn][i] + bb;
            }
        }
    }
}

extern "C" void kernel_launch(void* const* d_in, const int* in_sizes, int n_in,
                              void* d_out, int out_size, void* d_ws, size_t ws_size,
                              hipStream_t stream)
{
    const float* input    = (const float*)d_in[0];
    const int*   adj_rows = (const int*)d_in[1];
    const int*   adj_cols = (const int*)d_in[2];
    const float* adj_vals = (const float*)d_in[3];
    const float* gamma1   = (const float*)d_in[4];
    const float* beta1    = (const float*)d_in[5];
    const float* W1       = (const float*)d_in[6];
    const float* b1       = (const float*)d_in[7];
    const float* gamma2   = (const float*)d_in[8];
    const float* beta2    = (const float*)d_in[9];
    const float* W2       = (const float*)d_in[10];
    const float* b2       = (const float*)d_in[11];

    int n = in_sizes[0] / N_D;   // 100000
    int E = in_sizes[1];         // 1600000
    size_t n_pad = ((size_t)n + 127) & ~(size_t)127;

    u16* xbf = (u16*)d_ws;                         // n_pad*256 bf16
    u16* ybf = xbf + n_pad * 256;                  // n_pad*256 bf16
    int2* edges = (int2*)ybf;                      // E int2 (aliases ybf; consumed pre-gemm1)
    int2* staged = edges + E;                      // NB*PERB int2 (also in ybf region)
    u16* W1bt = ybf + n_pad * 256;                 // 256*256 bf16
    u16* W2bt = W1bt + 256 * 256;                  // 128*256 bf16
    float* stats  = (float*)(W2bt + 128 * 256);
    float* a1     = stats;
    float* c1     = stats + 256;
    float* b1p    = stats + 512;
    float* a2     = stats + 768;
    float* c2     = stats + 1024;
    float* s1s    = stats + 1280;                  // NS1*512 floats
    float* s2s    = s1s + NS1 * 512;               // NS2*512 floats
    int* cursor     = (int*)(s2s + NS2 * 512);     // NB*CPAD ints (64B-padded)
    int* bucketBase = cursor + NB * CPAD;          // NB ints
    int* rowPtr     = bucketBase + NB;             // n ints
    int* cnt        = rowPtr + n;                  // n ints

    hipMemsetAsync(cursor, 0, (size_t)NB * CPAD * sizeof(int), stream);
    hipMemsetAsync(s1s, 0, (size_t)(NS1 + NS2) * 512 * sizeof(float), stream);

    convin_kernel<<<(n * 32 + 255) / 256, 256, 0, stream>>>(input, xbf, n);
    convw2_kernel<<<128, 256, 0, stream>>>(W2, W2bt);

    // bucket magic: b = umulhi(r, inv_pr) == r / per_rows for r < 2^17
    int per_rows = (n + NB - 1) / NB;                       // 98
    unsigned inv_pr = (unsigned)((((unsigned long long)1 << 32) + per_rows - 1) / per_rows);

    bucket_kernel<<<256, 1024, 0, stream>>>(
        adj_rows, adj_cols, adj_vals, cursor, staged, E, inv_pr, per_rows);
    scan_buckets_kernel<<<1, 1024, 0, stream>>>(cursor, bucketBase);
    place_kernel<<<NB, 256, 0, stream>>>(
        cursor, bucketBase, staged, edges, rowPtr, cnt, n, per_rows);

    aggregate_kernel<<<(n + 3) / 4, 256, 0, stream>>>(
        (const unsigned*)xbf, rowPtr, cnt, edges, (unsigned*)xbf, n);

    xstats_kernel<<<(n + STAT_ROWS - 1) / STAT_ROWS, 256, 0, stream>>>(xbf, s1s, n);

    prep1a_kernel<<<1, 256, 0, stream>>>(s1s, gamma1, beta1, a1, c1, (float)n);
    convw1_kernel<<<256, 256, 0, stream>>>(W1, a1, c1, b1, W1bt, b1p);

    dim3 g1((unsigned)(n_pad / 128), 2);
    gemm1_kernel<<<g1, 256, 0, stream>>>(xbf, W1bt, b1p, ybf, s2s, n);

    prep2_kernel<<<1, 256, 0, stream>>>(s2s, gamma2, beta2, a2, c2, (float)n);

    gemm2_kernel<<<(unsigned)(n_pad / 128), 256, 0, stream>>>(ybf, W2bt, a2, c2, b2, (float*)d_out, n);
}